// Round 16
// baseline (5100.229 us; speedup 1.0000x reference)
//
#include <hip/hip_runtime.h>
#include <math.h>

// f32(-log(2048)), f32(log(1024)-log(2048)) from f64 constants:
#define NORM_F  ((float)(-7.6246189861593984953))
#define BIN_F   ((float)(-0.6931471805599453094))

__device__ __forceinline__ float exp_cr(float x) { return (float)exp((double)x); }
__device__ __forceinline__ float log_cr(float x) { return (float)log((double)x); }

// ======================= structs for batched GEMM jobs =======================
struct GJob {
  const float* A0; const float* X0;
  const float* A1; const float* X1;
  const float* A2; const float* X2;
  const float* bias; float* C;
  const float* resid;            // if non-null: C = resid + (acc + bias)
};
struct GArgs { GJob j[8]; };

struct TJob { const float* A; const float* B; float* C; int cb; };
struct TArgs { TJob j[8]; };

struct VJob { const float* V; const float* P; float* C; };
struct VArgs { VJob j[8]; };

struct NJob { const float* A; const float* B; float* C; };
struct NArgs { NJob j[2]; };

#define MICRO_FMA(w4, x4)                                   \
  acc[0][0] = fmaf(w4.x, x4.x, acc[0][0]);                  \
  acc[0][1] = fmaf(w4.x, x4.y, acc[0][1]);                  \
  acc[0][2] = fmaf(w4.x, x4.z, acc[0][2]);                  \
  acc[0][3] = fmaf(w4.x, x4.w, acc[0][3]);                  \
  acc[1][0] = fmaf(w4.y, x4.x, acc[1][0]);                  \
  acc[1][1] = fmaf(w4.y, x4.y, acc[1][1]);                  \
  acc[1][2] = fmaf(w4.y, x4.z, acc[1][2]);                  \
  acc[1][3] = fmaf(w4.y, x4.w, acc[1][3]);                  \
  acc[2][0] = fmaf(w4.z, x4.x, acc[2][0]);                  \
  acc[2][1] = fmaf(w4.z, x4.y, acc[2][1]);                  \
  acc[2][2] = fmaf(w4.z, x4.z, acc[2][2]);                  \
  acc[2][3] = fmaf(w4.z, x4.w, acc[2][3]);                  \
  acc[3][0] = fmaf(w4.w, x4.x, acc[3][0]);                  \
  acc[3][1] = fmaf(w4.w, x4.y, acc[3][1]);                  \
  acc[3][2] = fmaf(w4.w, x4.z, acc[3][2]);                  \
  acc[3][3] = fmaf(w4.w, x4.w, acc[3][3]);

// ======================= concat for keypoint encoder =========================
__global__ __launch_bounds__(256) void concat_kenc(
    const float* __restrict__ h1, const float* __restrict__ h2,
    const float* __restrict__ uc1, const float* __restrict__ uc2,
    const float* __restrict__ s1, const float* __restrict__ s2,
    float* __restrict__ out) {
  int img = blockIdx.y;
  const float* h  = img ? h2 : h1;
  const float* uc = img ? uc2 : uc1;
  const float* sc = img ? s2 : s1;
  float* o = out + (size_t)img * 260 * 1024;
  int idx = blockIdx.x * 256 + threadIdx.x;
  if (idx >= 260 * 1024) return;
  int c = idx >> 10, n = idx & 1023;
  float v;
  if (c < 256)      v = h[(size_t)n * 256 + c];
  else if (c < 259) v = uc[(size_t)n * 3 + (c - 256)];
  else              v = sc[n];
  o[idx] = v;
}

// == C(co x 1024) = segs A@X + bias (+resid). 512 thr, 32x64 tile, 1x4 micro ==
__global__ __launch_bounds__(512) void gemm_std(GArgs args, int nseg, int split,
                                                int ci0, int ci1, int ci2,
                                                int lda, int co) {
  __shared__ float Wt[32][36];
  __shared__ float Xs[32][68];
  GJob jb = args.j[blockIdx.z];
  const int n0 = blockIdx.x * 64;
  const int c0 = blockIdx.y * 32;
  const int t = threadIdx.x, tx = t & 15, ty = t >> 4;   // ty 0..31
  float acc[4] = {};
  float accT[4] = {};
  const float* As[3] = { jb.A0, jb.A1, jb.A2 };
  const float* Xp[3] = { jb.X0, jb.X1, jb.X2 };
  int cis[3] = { ci0, ci1, ci2 };
  for (int s = 0; s < nseg; ++s) {
    const float* A = As[s];
    const float* X = Xp[s];
    const int ci = cis[s];
    if (split) {
      #pragma unroll
      for (int jj = 0; jj < 4; ++jj) acc[jj] = 0.f;
    }
    for (int k0 = 0; k0 < ci; k0 += 32) {
      if (t < 256) {  // W stage: 32 rows x 32 k
        const int row = t >> 3;
        const int kk = (t & 7) * 4;
        const float* srcp = A + (size_t)(c0 + row) * lda + k0 + kk;
        float4 w4;
        if (k0 + kk + 4 <= ci) {
          w4 = *(const float4*)srcp;
        } else {
          w4.x = (k0 + kk + 0 < ci) ? srcp[0] : 0.f;
          w4.y = (k0 + kk + 1 < ci) ? srcp[1] : 0.f;
          w4.z = (k0 + kk + 2 < ci) ? srcp[2] : 0.f;
          w4.w = (k0 + kk + 3 < ci) ? srcp[3] : 0.f;
        }
        Wt[kk + 0][row] = w4.x; Wt[kk + 1][row] = w4.y;
        Wt[kk + 2][row] = w4.z; Wt[kk + 3][row] = w4.w;
      }
      {  // X stage
        const int kk = t >> 4, nl = (t & 15) * 4;
        float4 x4 = make_float4(0.f, 0.f, 0.f, 0.f);
        if (k0 + kk < ci) x4 = *(const float4*)(X + (size_t)(k0 + kk) * 1024 + n0 + nl);
        *(float4*)&Xs[kk][nl] = x4;
      }
      __syncthreads();
      #pragma unroll
      for (int kk = 0; kk < 32; ++kk) {
        const float w0 = Wt[kk][ty];
        const float4 x4 = *(const float4*)&Xs[kk][tx * 4];
        acc[0] = fmaf(w0, x4.x, acc[0]);
        acc[1] = fmaf(w0, x4.y, acc[1]);
        acc[2] = fmaf(w0, x4.z, acc[2]);
        acc[3] = fmaf(w0, x4.w, acc[3]);
      }
      __syncthreads();
    }
    if (split) {
      #pragma unroll
      for (int jj = 0; jj < 4; ++jj)
        accT[jj] = __fadd_rn(accT[jj], acc[jj]);
    }
  }
  {
    const int row = c0 + ty;
    const float b = jb.bias ? jb.bias[row] : 0.f;
    const float* src = split ? accT : acc;
    float4 o;
    o.x = __fadd_rn(src[0], b); o.y = __fadd_rn(src[1], b);
    o.z = __fadd_rn(src[2], b); o.w = __fadd_rn(src[3], b);
    if (jb.resid) {
      const float4 r4 = *(const float4*)(jb.resid + (size_t)row * 1024 + n0 + tx * 4);
      o.x = __fadd_rn(r4.x, o.x); o.y = __fadd_rn(r4.y, o.y);
      o.z = __fadd_rn(r4.z, o.z); o.w = __fadd_rn(r4.w, o.w);
    }
    *(float4*)(jb.C + (size_t)row * 1024 + n0 + tx * 4) = o;
  }
}

// ========== C[n][m] = scale * sum_k A[(cb+k*cs)*1024+n]*B[(cb+k*cs)*1024+m] ==
__global__ __launch_bounds__(256) void gemm_tn(TArgs args, int K, int cs,
                                               float scale, int ldc) {
  __shared__ float As[64][68];
  __shared__ float Bs[64][68];
  TJob jb = args.j[blockIdx.z];
  const int m0 = blockIdx.x * 64;
  const int n0 = blockIdx.y * 64;
  const int t = threadIdx.x, tx = t & 15, ty = t >> 4;
  float acc[4][4] = {};
  for (int k0 = 0; k0 < K; k0 += 64) {
    #pragma unroll
    for (int q = 0; q < 4; ++q) {
      const int kk = (t >> 4) + q * 16;
      const int col = (t & 15) * 4;
      const size_t rb = (size_t)(jb.cb + (k0 + kk) * cs) * 1024;
      *(float4*)&As[kk][col] = *(const float4*)(jb.A + rb + n0 + col);
      *(float4*)&Bs[kk][col] = *(const float4*)(jb.B + rb + m0 + col);
    }
    __syncthreads();
    #pragma unroll 16
    for (int kk = 0; kk < 64; ++kk) {
      const float4 w4 = *(const float4*)&As[kk][ty * 4];
      const float4 x4 = *(const float4*)&Bs[kk][tx * 4];
      MICRO_FMA(w4, x4)
    }
    __syncthreads();
  }
  #pragma unroll
  for (int i = 0; i < 4; ++i) {
    float4 o;
    o.x = __fmul_rn(acc[i][0], scale); o.y = __fmul_rn(acc[i][1], scale);
    o.z = __fmul_rn(acc[i][2], scale); o.w = __fmul_rn(acc[i][3], scale);
    *(float4*)(jb.C + (size_t)(n0 + ty * 4 + i) * ldc + m0 + tx * 4) = o;
  }
}

// == msg: C[d][n] = sum_m V[d*4096+m] P[n*1024+m]; 512 thr, conflict-free pads
__global__ __launch_bounds__(512) void gemm_vp(VArgs args) {
  __shared__ float Vs[64][33];
  __shared__ float Ps[64][65];
  VJob jb = args.j[blockIdx.z];
  const int n0 = blockIdx.x * 64;
  const int d0 = blockIdx.y * 32;
  const int t = threadIdx.x, tx = t & 15, ty = t >> 4;   // ty 0..31
  float acc[4] = {};
  for (int m0 = 0; m0 < 1024; m0 += 64) {
    {  // V stage: one float4 per thread
      const int d = t >> 4, m4 = (t & 15) * 4;
      float4 v4 = *(const float4*)(jb.V + (size_t)(d0 + d) * 4096 + m0 + m4);
      Vs[m4 + 0][d] = v4.x; Vs[m4 + 1][d] = v4.y;
      Vs[m4 + 2][d] = v4.z; Vs[m4 + 3][d] = v4.w;
    }
    #pragma unroll
    for (int q = 0; q < 2; ++q) {  // P stage: two float4 per thread
      const int idx = t + q * 512;
      const int n = idx >> 4, m4 = (idx & 15) * 4;
      float4 p4 = *(const float4*)(jb.P + (size_t)(n0 + n) * 1024 + m0 + m4);
      Ps[m4 + 0][n] = p4.x; Ps[m4 + 1][n] = p4.y;
      Ps[m4 + 2][n] = p4.z; Ps[m4 + 3][n] = p4.w;
    }
    __syncthreads();
    #pragma unroll
    for (int mm = 0; mm < 64; ++mm) {
      const float v = Vs[mm][ty];
      acc[0] = fmaf(v, Ps[mm][tx * 4 + 0], acc[0]);
      acc[1] = fmaf(v, Ps[mm][tx * 4 + 1], acc[1]);
      acc[2] = fmaf(v, Ps[mm][tx * 4 + 2], acc[2]);
      acc[3] = fmaf(v, Ps[mm][tx * 4 + 3], acc[3]);
    }
    __syncthreads();
  }
  {
    float4 o;
    o.x = acc[0]; o.y = acc[1]; o.z = acc[2]; o.w = acc[3];
    *(float4*)(jb.C + (size_t)(d0 + ty) * 4096 + n0 + tx * 4) = o;
  }
}

// == prop: C[c][d] = scale * sum_s A[c][s]B[d][s]; 512 thr, 32x64, pads fixed =
// Per-output chain: ascending s, single fmaf accumulator — bit-identical.
__global__ __launch_bounds__(512) void gemm_nt(NArgs args, float scale) {
  __shared__ float Cs[64][33];
  __shared__ float Ds[64][65];
  NJob jb = args.j[blockIdx.z];
  const int d0 = blockIdx.x * 64;
  const int c0 = blockIdx.y * 32;
  const int t = threadIdx.x, tx = t & 15, ty = t >> 4;   // ty 0..31
  float acc[4] = {};
  for (int s0 = 0; s0 < 1024; s0 += 64) {
    {  // A stage: 32 rows x 64 s, one float4 per thread
      const int c = t >> 4, s4 = (t & 15) * 4;
      float4 a4 = *(const float4*)(jb.A + (size_t)(c0 + c) * 1024 + s0 + s4);
      Cs[s4 + 0][c] = a4.x; Cs[s4 + 1][c] = a4.y;
      Cs[s4 + 2][c] = a4.z; Cs[s4 + 3][c] = a4.w;
    }
    #pragma unroll
    for (int q = 0; q < 2; ++q) {  // B stage: 64 rows x 64 s, two float4/thread
      const int idx = t + q * 512;
      const int d = idx >> 4, s4 = (idx & 15) * 4;
      float4 b4 = *(const float4*)(jb.B + (size_t)(d0 + d) * 1024 + s0 + s4);
      Ds[s4 + 0][d] = b4.x; Ds[s4 + 1][d] = b4.y;
      Ds[s4 + 2][d] = b4.z; Ds[s4 + 3][d] = b4.w;
    }
    __syncthreads();
    #pragma unroll
    for (int ss = 0; ss < 64; ++ss) {
      const float a = Cs[ss][ty];
      acc[0] = fmaf(a, Ds[ss][tx * 4 + 0], acc[0]);
      acc[1] = fmaf(a, Ds[ss][tx * 4 + 1], acc[1]);
      acc[2] = fmaf(a, Ds[ss][tx * 4 + 2], acc[2]);
      acc[3] = fmaf(a, Ds[ss][tx * 4 + 3], acc[3]);
    }
    __syncthreads();
  }
  {
    float4 o;
    o.x = __fmul_rn(acc[0], scale); o.y = __fmul_rn(acc[1], scale);
    o.z = __fmul_rn(acc[2], scale); o.w = __fmul_rn(acc[3], scale);
    *(float4*)(jb.C + (size_t)(c0 + ty) * 1024 + d0 + tx * 4) = o;
  }
}

// ===== build adjacency ones ==================================================
__global__ __launch_bounds__(64) void scatter_adj(const int* __restrict__ nbr,
                                                  float* __restrict__ adj) {
  const int i = blockIdx.x, img = blockIdx.y;
  const int t = threadIdx.x;
  if (t >= 20) return;
  const int dst = nbr[((size_t)img * 1024 + i) * 20 + t];
  adj[(size_t)img * 1048576 + (size_t)dst * 1024 + i] = 1.0f;
}

// == bn+relu: stage to LDS; ONE wave runs the exact sequential chains =========
__global__ __launch_bounds__(256) void bn_relu_par(float* __restrict__ x,
                                                   const float* __restrict__ g,
                                                   const float* __restrict__ be,
                                                   int co) {
  const int ch = blockIdx.x, img = blockIdx.y;
  float* p = x + ((size_t)img * co + ch) * 1024;
  __shared__ float ls[1024];
  __shared__ float sh[2];
  const int t = threadIdx.x;
  #pragma unroll
  for (int q = 0; q < 4; ++q) ls[t + q * 256] = p[t + q * 256];
  __syncthreads();
  if (t < 64) {
    float s = 0.f;
    for (int n = 0; n < 1024; ++n) s = __fadd_rn(s, ls[n]);
    const float mean = __fdiv_rn(s, 1024.f);
    float vs = 0.f;
    for (int n = 0; n < 1024; ++n) {
      const float d = __fsub_rn(ls[n], mean);
      vs = __fadd_rn(vs, __fmul_rn(d, d));
    }
    const float var = __fdiv_rn(vs, 1024.f);
    if (t == 0) {
      sh[0] = mean;
      sh[1] = __fdiv_rn(1.f, sqrtf(__fadd_rn(var, 1e-5f)));
    }
  }
  __syncthreads();
  const float mean = sh[0], rs = sh[1];
  const float gc = g[ch], bc = be[ch];
  #pragma unroll
  for (int q = 0; q < 4; ++q) {
    const int n = t + q * 256;
    float v = __fmul_rn(gc, __fsub_rn(ls[n], mean));
    v = __fmul_rn(v, rs);
    v = __fadd_rn(v, bc);
    p[n] = fmaxf(v, 0.f);
  }
}

// == KNN top-20 (unchanged) ===================================================
__global__ __launch_bounds__(256) void knn_kernel(const float* __restrict__ uc1,
                                                  const float* __restrict__ uc2,
                                                  int* __restrict__ nbr) {
  const int i = blockIdx.x, img = blockIdx.y;
  const float* uc = img ? uc2 : uc1;
  __shared__ float dist[1024];
  __shared__ float rv[256];
  __shared__ int   ri[256];
  const int t = threadIdx.x;
  const float pix = uc[i * 3], piy = uc[i * 3 + 1], piz = uc[i * 3 + 2];
  const float sqi = fmaf(piz, piz, fmaf(piy, piy, __fmul_rn(pix, pix)));
  for (int j = t; j < 1024; j += 256) {
    const float x = uc[j * 3], y = uc[j * 3 + 1], z = uc[j * 3 + 2];
    const float gg  = fmaf(piz, z, fmaf(piy, y, __fmul_rn(pix, x)));
    const float sqj = fmaf(z, z, fmaf(y, y, __fmul_rn(x, x)));
    const float d = __fsub_rn(__fadd_rn(sqi, sqj), __fmul_rn(2.f, gg));
    dist[j] = (j == i) ? INFINITY : d;
  }
  __syncthreads();
  int* out = nbr + ((size_t)img * 1024 + i) * 20;
  for (int k = 0; k < 20; ++k) {
    float bv = INFINITY; int bi = 0x7fffffff;
    for (int j = t; j < 1024; j += 256) {
      const float d = dist[j];
      if (d < bv) { bv = d; bi = j; }
    }
    rv[t] = bv; ri[t] = bi;
    __syncthreads();
    for (int st = 128; st > 0; st >>= 1) {
      if (t < st) {
        const float v2 = rv[t + st]; const int i2 = ri[t + st];
        if (v2 < rv[t] || (v2 == rv[t] && i2 < ri[t])) { rv[t] = v2; ri[t] = i2; }
      }
      __syncthreads();
    }
    if (t == 0) { out[k] = ri[0]; dist[ri[0]] = INFINITY; }
    __syncthreads();
  }
}

// ======================= o = a*x + b*y, no-FMA per-op rounding ===============
__global__ __launch_bounds__(256) void axpby(const float* __restrict__ x,
                                             const float* __restrict__ y,
                                             float* __restrict__ o,
                                             float a, float b, int n) {
  const int i = blockIdx.x * 256 + threadIdx.x;
  if (i < n) o[i] = __fadd_rn(__fmul_rn(a, x[i]), __fmul_rn(b, y[i]));
}

// == softmax row: tree-max + parallel exp; ONE wave runs the exact sum chain ==
__global__ __launch_bounds__(256) void softmax_par(float* __restrict__ P) {
  float* p = P + (size_t)blockIdx.x * 1024;
  __shared__ float ls[1024];
  __shared__ float red[256];
  const int t = threadIdx.x;
  float mx = -INFINITY;
  #pragma unroll
  for (int q = 0; q < 4; ++q) {
    const float v = p[t + q * 256];
    ls[t + q * 256] = v;
    mx = fmaxf(mx, v);
  }
  red[t] = mx;
  __syncthreads();
  for (int st = 128; st > 0; st >>= 1) { if (t < st) red[t] = fmaxf(red[t], red[t + st]); __syncthreads(); }
  mx = red[0];
  __syncthreads();
  #pragma unroll
  for (int q = 0; q < 4; ++q) {
    const int n = t + q * 256;
    ls[n] = exp_cr(__fsub_rn(ls[n], mx));
  }
  __syncthreads();
  if (t < 64) {
    float s = 0.f;
    for (int n = 0; n < 1024; ++n) s = __fadd_rn(s, ls[n]);  // exact serial chain
    if (t == 0) red[0] = s;
  }
  __syncthreads();
  const float s = red[0];
  #pragma unroll
  for (int q = 0; q < 4; ++q) {
    const int n = t + q * 256;
    p[n] = __fdiv_rn(ls[n], s);
  }
}

// ======================= build Z and Z^T (f32 copies) ========================
__global__ __launch_bounds__(256) void build_Z(const float* __restrict__ sc,
                                               const float* __restrict__ alpha,
                                               float* __restrict__ Z,
                                               float* __restrict__ ZT) {
  const int idx = blockIdx.x * 256 + threadIdx.x;
  if (idx >= 1025 * 1025) return;
  const int i = idx / 1025, j = idx - i * 1025;
  const float v = (i < 1024 && j < 1024) ? sc[(size_t)i * 1024 + j] : alpha[0];
  Z[idx] = v;
  ZT[(size_t)j * 1025 + i] = v;
}

// == lse row: stage + tree-max + parallel exp; ONE wave runs exact sum chain ==
__global__ __launch_bounds__(256) void lse_par(const float* __restrict__ M,
                                               const float* __restrict__ add,
                                               float* __restrict__ out) {
  const int r = blockIdx.x;
  const float* p = M + (size_t)r * 1025;
  __shared__ float ls[1025];
  __shared__ float red[256];
  const int t = threadIdx.x;
  float mx = -INFINITY;
  for (int j = t; j < 1025; j += 256) {
    const float v = __fadd_rn(p[j], add[j]);
    ls[j] = v;
    mx = fmaxf(mx, v);
  }
  red[t] = mx;
  __syncthreads();
  for (int st = 128; st > 0; st >>= 1) { if (t < st) red[t] = fmaxf(red[t], red[t + st]); __syncthreads(); }
  mx = red[0];
  __syncthreads();
  for (int j = t; j < 1025; j += 256) ls[j] = exp_cr(__fsub_rn(ls[j], mx));
  __syncthreads();
  if (t < 64) {
    float s = 0.f;
    for (int j = 0; j < 1025; ++j) s = __fadd_rn(s, ls[j]);  // exact serial chain
    if (t == 0) {
      const float logw = (r < 1024) ? NORM_F : BIN_F;
      out[r] = __fsub_rn(logw, __fadd_rn(log_cr(s), mx));
    }
  }
}

// == final Z = ((Z + u) + v) - norm_f32; outZ + col-major copy ================
__global__ __launch_bounds__(256) void write_final(const float* __restrict__ Z,
                                                   const float* __restrict__ u,
                                                   const float* __restrict__ v,
                                                   float* __restrict__ outZ,
                                                   float* __restrict__ FZc) {
  const int idx = blockIdx.x * 256 + threadIdx.x;
  if (idx >= 1025 * 1025) return;
  const int i = idx / 1025, j = idx - i * 1025;
  float t = __fadd_rn(Z[idx], u[i]);
  t = __fadd_rn(t, v[j]);
  t = __fsub_rn(t, NORM_F);
  outZ[idx] = t;
  FZc[(size_t)j * 1025 + i] = t;
}

// == argmax row: tie-aware tree (== first-index sequential) ===================
__global__ __launch_bounds__(256) void argmax_par(const float* __restrict__ M,
                                                  float* __restrict__ maxout,
                                                  int* __restrict__ idxout) {
  const int r = blockIdx.x;
  const float* p = M + (size_t)r * 1025;
  __shared__ float rv[256];
  __shared__ int   ri[256];
  const int t = threadIdx.x;
  float bv = -INFINITY; int bi = 0x7fffffff;
  for (int j = t; j < 1024; j += 256) {
    const float v = p[j];
    if (v > bv) { bv = v; bi = j; }
  }
  rv[t] = bv; ri[t] = bi;
  __syncthreads();
  for (int st = 128; st > 0; st >>= 1) {
    if (t < st) {
      const float v2 = rv[t + st]; const int i2 = ri[t + st];
      if (v2 > rv[t] || (v2 == rv[t] && i2 < ri[t])) { rv[t] = v2; ri[t] = i2; }
    }
    __syncthreads();
  }
  if (t == 0) {
    idxout[r] = ri[0];
    if (maxout) maxout[r] = rv[0];
  }
}

// ======================= mutual matching =====================================
__global__ __launch_bounds__(256) void matches_kernel(const int* __restrict__ idx1,
                                                      const int* __restrict__ idx2,
                                                      const float* __restrict__ rowmax,
                                                      float* __restrict__ m_out,
                                                      float* __restrict__ s_out) {
  const int i = blockIdx.x * 256 + threadIdx.x;
  if (i >= 1024) return;
  const int j = idx1[i];
  const bool mutual = (idx2[j] == i);
  const float msc = mutual ? exp_cr(rowmax[i]) : 0.f;
  s_out[i] = msc;
  m_out[i] = (mutual && msc > 0.2f) ? (float)j : -1.f;
}

// ============================================================================
extern "C" void kernel_launch(void* const* d_in, const int* in_sizes, int n_in,
                              void* d_out, int out_size, void* d_ws, size_t ws_size,
                              hipStream_t stream) {
  const float* h1  = (const float*)d_in[0];
  const float* h2  = (const float*)d_in[1];
  const float* uc1 = (const float*)d_in[2];
  const float* uc2 = (const float*)d_in[3];
  const float* s1  = (const float*)d_in[4];
  const float* s2  = (const float*)d_in[5];
  const float* kw[5]  = { (const float*)d_in[6],  (const float*)d_in[8],
                          (const float*)d_in[10], (const float*)d_in[12],
                          (const float*)d_in[14] };
  const float* kb[5]  = { (const float*)d_in[7],  (const float*)d_in[9],
                          (const float*)d_in[11], (const float*)d_in[13],
                          (const float*)d_in[15] };
  const float* kg[4]  = { (const float*)d_in[16], (const float*)d_in[18],
                          (const float*)d_in[20], (const float*)d_in[22] };
  const float* kbe[4] = { (const float*)d_in[17], (const float*)d_in[19],
                          (const float*)d_in[21], (const float*)d_in[23] };
  const float* cheb_w = (const float*)d_in[24];
  const float* cheb_b = (const float*)d_in[25];
  const float* pw = (const float*)d_in[26];
  const float* pb = (const float*)d_in[27];
  const float* mw = (const float*)d_in[28];
  const float* mb = (const float*)d_in[29];
  const float* m1w = (const float*)d_in[30];
  const float* m1b = (const float*)d_in[31];
  const float* gg  = (const float*)d_in[32];
  const float* gbe = (const float*)d_in[33];
  const float* m2w = (const float*)d_in[34];
  const float* m2b = (const float*)d_in[35];
  const float* fpw = (const float*)d_in[36];
  const float* fpb = (const float*)d_in[37];
  const float* bin = (const float*)d_in[38];

  float* ws = (float*)d_ws;
  float* A0   = ws;                 // 1048576
  float* A1   = ws + 1048576;       // 1048576
  float* Dm   = ws + 2097152;       // 524288
  float* DT   = ws + 2621440;       // 524288
  float* TX1  = ws + 3145728;       // 524288
  float* TX2  = ws + 3670016;       // 524288
  float* QKV  = ws + 4194304;       // 1572864
  float* PROB = ws + 5767168;       // 8388608 (adjacency early; probs; SC late)
  float* ADJ = PROB;
  float* SCp = PROB;
  float* Zb  = ws;                  // 1050625
  float* ZTb = ws + 1050628;        // 1050625
  float* FZc = ws + 3151884;        // 1050625
  float* Ub  = ws + 4202512;        // 1025
  float* Vb  = ws + 4203540;        // 1025
  float* RM  = ws + 4204568;        // 1024
  int*   I1  = (int*)(ws + 4205592);
  int*   I2  = (int*)(ws + 4206616);
  int*   KNNI = (int*)QKV;
  float* MSG   = A1;
  float* T1    = A0;
  float* outF  = (float*)d_out;
  float* outZ  = outF;
  float* outM  = outF + 1050625;
  float* outS  = outF + 1051649;
  float* outMD1 = outF + 1052673;
  float* outMD2 = outF + 1314817;
  (void)ws_size; (void)in_sizes; (void)n_in; (void)out_size;

  // ---------------- 1. kenc ----------------
  concat_kenc<<<dim3(1040, 2), 256, 0, stream>>>(h1, h2, uc1, uc2, s1, s2, A0);

  const int kci[5] = { 260, 64, 128, 256, 512 };
  const int kco[5] = { 64, 128, 256, 512, 256 };
  float* ping = A0; float* pong = A1;
  for (int L = 0; L < 5; ++L) {
    const int ci = kci[L], co = kco[L];
    float* dst = (L == 4) ? DT : pong;
    GArgs ga = {};
    for (int img = 0; img < 2; ++img) {
      ga.j[img].A0 = kw[L];
      ga.j[img].X0 = ping + (size_t)img * ci * 1024;
      ga.j[img].bias = kb[L];
      ga.j[img].C = dst + (size_t)img * co * 1024;
    }
    gemm_std<<<dim3(16, co / 32, 2), 512, 0, stream>>>(ga, 1, 0, ci, 0, 0, ci, co);
    if (L < 4)
      bn_relu_par<<<dim3(co, 2), 256, 0, stream>>>(dst, kg[L], kbe[L], co);
    float* tmp = ping; ping = pong; pong = tmp;
  }

  // ---------------- 2. knn + chebconv ----------------
  knn_kernel<<<dim3(1024, 2), 256, 0, stream>>>(uc1, uc2, KNNI);
  hipMemsetAsync(ADJ, 0, 2u * 1048576u * sizeof(float), stream);
  scatter_adj<<<dim3(1024, 2), 64, 0, stream>>>(KNNI, ADJ);

  {
    NArgs na = {};
    for (int img = 0; img < 2; ++img) {
      na.j[img].A = DT + (size_t)img * 262144;
      na.j[img].B = ADJ + (size_t)img * 1048576;
      na.j[img].C = TX1 + (size_t)img * 262144;
    }
    gemm_nt<<<dim3(16, 8, 2), 512, 0, stream>>>(na, -0.05f);
  }
  {
    NArgs na = {};
    for (int img = 0; img < 2; ++img) {
      na.j[img].A = TX1 + (size_t)img * 262144;
      na.j[img].B = ADJ + (size_t)img * 1048576;
      na.j[img].C = A0 + (size_t)img * 262144;
    }
    gemm_nt<<<dim3(16, 8, 2), 512, 0, stream>>>(na, -0.05f);
  }
  axpby<<<2048, 256, 0, stream>>>(A0, DT, TX2, 2.f, -1.f, 524288);

  {
    GArgs ga = {};
    for (int img = 0; img < 2; ++img) {
      ga.j[img].A0 = cheb_w;           ga.j[img].X0 = DT  + (size_t)img * 262144;
      ga.j[img].A1 = cheb_w + 65536;   ga.j[img].X1 = TX1 + (size_t)img * 262144;
      ga.j[img].A2 = cheb_w + 131072;  ga.j[img].X2 = TX2 + (size_t)img * 262144;
      ga.j[img].bias = cheb_b;
      ga.j[img].C = Dm + (size_t)img * 262144;
    }
    gemm_std<<<dim3(16, 8, 2), 512, 0, stream>>>(ga, 3, 1, 256, 256, 256, 256, 256);
  }

  // ---------------- 3. GNN layers ----------------
  float* qb = QKV;
  float* kb_ = QKV + 524288;
  float* vb = QKV + 1048576;
  float* MSG2 = QKV;
  for (int l = 0; l < 18; ++l) {
    const int cross = l & 1;
    const float* x[2]   = { Dm, Dm + 262144 };
    const float* src[2] = { cross ? x[1] : x[0], cross ? x[0] : x[1] };

    {
      GArgs ga = {};
      for (int p = 0; p < 3; ++p)
        for (int img = 0; img < 2; ++img) {
          GJob& j = ga.j[p * 2 + img];
          j.A0 = pw + ((size_t)(l * 3 + p)) * 65536;
          j.X0 = (p == 0) ? x[img] : src[img];
          j.bias = pb + ((size_t)(l * 3 + p)) * 256;
          j.C = QKV + ((size_t)(p * 2 + img)) * 262144;
        }
      gemm_std<<<dim3(16, 8, 6), 512, 0, stream>>>(ga, 1, 0, 256, 0, 0, 256, 256);
    }
    {
      TArgs ta = {};
      for (int img = 0; img < 2; ++img)
        for (int h = 0; h < 4; ++h) {
          TJob& j = ta.j[img * 4 + h];
          j.A = qb + (size_t)img * 262144;
          j.B = kb_ + (size_t)img * 262144;
          j.C = PROB + ((size_t)(img * 4 + h)) * 1048576;
          j.cb = h;
        }
      gemm_tn<<<dim3(16, 16, 8), 256, 0, stream>>>(ta, 64, 4, 0.125f, 1024);
    }
    softmax_par<<<8192, 256, 0, stream>>>(PROB);
    {
      VArgs va = {};
      for (int img = 0; img < 2; ++img)
        for (int h = 0; h < 4; ++h) {
          VJob& j = va.j[img * 4 + h];
          j.V = vb + (size_t)img * 262144 + h * 1024;
          j.P = PROB + ((size_t)(img * 4 + h)) * 1048576;
          j.C = MSG + (size_t)img * 262144 + h * 1024;
        }
      gemm_vp<<<dim3(16, 2, 8), 512, 0, stream>>>(va);
    }
    {
      GArgs ga = {};
      for (int img = 0; img < 2; ++img) {
        ga.j[img].A0 = mw + (size_t)l * 65536;
        ga.j[img].X0 = MSG + (size_t)img * 262144;
        ga.j[img].bias = mb + (size_t)l * 256;
        ga.j[img].C = MSG2 + (size_t)img * 262144;
      }
      gemm_std<<<dim3(16, 8, 2), 512, 0, stream>>>(ga, 1, 0, 256, 0, 0, 256, 256);
    }
    {
      GArgs ga = {};
      for (int img = 0; img < 2; ++img) {
        ga.j[img].A0 = m1w + (size_t)l * 262144;        ga.j[img].X0 = x[img];
        ga.j[img].A1 = m1w + (size_t)l * 262144 + 256;  ga.j[img].X1 = MSG2 + (size_t)img * 262144;
        ga.j[img].bias = m1b + (size_t)l * 512;
        ga.j[img].C = T1 + (size_t)img * 524288;
      }
      gemm_std<<<dim3(16, 16, 2), 512, 0, stream>>>(ga, 2, 0, 256, 256, 0, 512, 512);
    }
    bn_relu_par<<<dim3(512, 2), 256, 0, stream>>>(T1, gg + (size_t)l * 512, gbe + (size_t)l * 512, 512);
    {
      // m2 with fused residual: Dm = Dm + (acc + bias)
      GArgs ga = {};
      for (int img = 0; img < 2; ++img) {
        ga.j[img].A0 = m2w + (size_t)l * 131072;
        ga.j[img].X0 = T1 + (size_t)img * 524288;
        ga.j[img].bias = m2b + (size_t)l * 256;
        ga.j[img].C = Dm + (size_t)img * 262144;
        ga.j[img].resid = Dm + (size_t)img * 262144;
      }
      gemm_std<<<dim3(16, 8, 2), 512, 0, stream>>>(ga, 1, 0, 512, 0, 0, 512, 256);
    }
  }

  // ---------------- 4. final projections + score matrix ----------------
  {
    GArgs ga = {};
    for (int img = 0; img < 2; ++img) {
      ga.j[img].A0 = fpw;
      ga.j[img].X0 = Dm + (size_t)img * 262144;
      ga.j[img].bias = fpb;
      ga.j[img].C = (img ? outMD2 : outMD1);
    }
    gemm_std<<<dim3(16, 8, 2), 512, 0, stream>>>(ga, 1, 0, 256, 0, 0, 256, 256);
  }
  {
    TArgs ta = {};
    ta.j[0].A = outMD1; ta.j[0].B = outMD2; ta.j[0].C = SCp; ta.j[0].cb = 0;
    gemm_tn<<<dim3(16, 16, 1), 256, 0, stream>>>(ta, 256, 1, 0.0625f, 1024);
  }

  // ---------------- 5. Sinkhorn ----------------
  build_Z<<<4105, 256, 0, stream>>>(SCp, bin, Zb, ZTb);
  hipMemsetAsync(Ub, 0, 1025 * sizeof(float), stream);
  hipMemsetAsync(Vb, 0, 1025 * sizeof(float), stream);
  for (int it = 0; it < 20; ++it) {
    lse_par<<<1025, 256, 0, stream>>>(Zb, Vb, Ub);
    lse_par<<<1025, 256, 0, stream>>>(ZTb, Ub, Vb);
  }
  write_final<<<4105, 256, 0, stream>>>(Zb, Ub, Vb, outZ, FZc);

  // ---------------- 6. matching ----------------
  argmax_par<<<1024, 256, 0, stream>>>(outZ, RM, I1);
  argmax_par<<<1024, 256, 0, stream>>>(FZc, (float*)nullptr, I2);
  matches_kernel<<<4, 256, 0, stream>>>(I1, I2, RM, outM, outS);
}

// Round 17
// 4551.163 us; speedup vs baseline: 1.1206x; 1.1206x over previous
//
#include <hip/hip_runtime.h>
#include <math.h>

// f32(-log(2048)), f32(log(1024)-log(2048)) from f64 constants:
#define NORM_F  ((float)(-7.6246189861593984953))
#define BIN_F   ((float)(-0.6931471805599453094))

__device__ __forceinline__ float exp_cr(float x) { return (float)exp((double)x); }
__device__ __forceinline__ float log_cr(float x) { return (float)log((double)x); }

// ======================= structs for batched GEMM jobs =======================
struct GJob {
  const float* A0; const float* X0;
  const float* A1; const float* X1;
  const float* A2; const float* X2;
  const float* bias; float* C;
  const float* resid;            // if non-null: C = resid + (acc + bias)
};
struct GArgs { GJob j[8]; };

struct TJob { const float* A; const float* B; float* C; int cb; };
struct TArgs { TJob j[8]; };

struct VJob { const float* V; const float* P; float* C; };
struct VArgs { VJob j[8]; };

struct NJob { const float* A; const float* B; float* C; };
struct NArgs { NJob j[2]; };

#define MICRO_FMA(w4, x4)                                   \
  acc[0][0] = fmaf(w4.x, x4.x, acc[0][0]);                  \
  acc[0][1] = fmaf(w4.x, x4.y, acc[0][1]);                  \
  acc[0][2] = fmaf(w4.x, x4.z, acc[0][2]);                  \
  acc[0][3] = fmaf(w4.x, x4.w, acc[0][3]);                  \
  acc[1][0] = fmaf(w4.y, x4.x, acc[1][0]);                  \
  acc[1][1] = fmaf(w4.y, x4.y, acc[1][1]);                  \
  acc[1][2] = fmaf(w4.y, x4.z, acc[1][2]);                  \
  acc[1][3] = fmaf(w4.y, x4.w, acc[1][3]);                  \
  acc[2][0] = fmaf(w4.z, x4.x, acc[2][0]);                  \
  acc[2][1] = fmaf(w4.z, x4.y, acc[2][1]);                  \
  acc[2][2] = fmaf(w4.z, x4.z, acc[2][2]);                  \
  acc[2][3] = fmaf(w4.z, x4.w, acc[2][3]);                  \
  acc[3][0] = fmaf(w4.w, x4.x, acc[3][0]);                  \
  acc[3][1] = fmaf(w4.w, x4.y, acc[3][1]);                  \
  acc[3][2] = fmaf(w4.w, x4.z, acc[3][2]);                  \
  acc[3][3] = fmaf(w4.w, x4.w, acc[3][3]);

// ======================= concat for keypoint encoder =========================
__global__ __launch_bounds__(256) void concat_kenc(
    const float* __restrict__ h1, const float* __restrict__ h2,
    const float* __restrict__ uc1, const float* __restrict__ uc2,
    const float* __restrict__ s1, const float* __restrict__ s2,
    float* __restrict__ out) {
  int img = blockIdx.y;
  const float* h  = img ? h2 : h1;
  const float* uc = img ? uc2 : uc1;
  const float* sc = img ? s2 : s1;
  float* o = out + (size_t)img * 260 * 1024;
  int idx = blockIdx.x * 256 + threadIdx.x;
  if (idx >= 260 * 1024) return;
  int c = idx >> 10, n = idx & 1023;
  float v;
  if (c < 256)      v = h[(size_t)n * 256 + c];
  else if (c < 259) v = uc[(size_t)n * 3 + (c - 256)];
  else              v = sc[n];
  o[idx] = v;
}

// == C(co x 1024) = segs A@X + bias (+resid). 512 thr, 32x64 tile, 1x4 micro ==
__global__ __launch_bounds__(512) void gemm_std(GArgs args, int nseg, int split,
                                                int ci0, int ci1, int ci2,
                                                int lda, int co) {
  __shared__ float Wt[32][36];
  __shared__ float Xs[32][68];
  GJob jb = args.j[blockIdx.z];
  const int n0 = blockIdx.x * 64;
  const int c0 = blockIdx.y * 32;
  const int t = threadIdx.x, tx = t & 15, ty = t >> 4;   // ty 0..31
  float acc[4] = {};
  float accT[4] = {};
  const float* As[3] = { jb.A0, jb.A1, jb.A2 };
  const float* Xp[3] = { jb.X0, jb.X1, jb.X2 };
  int cis[3] = { ci0, ci1, ci2 };
  for (int s = 0; s < nseg; ++s) {
    const float* A = As[s];
    const float* X = Xp[s];
    const int ci = cis[s];
    if (split) {
      #pragma unroll
      for (int jj = 0; jj < 4; ++jj) acc[jj] = 0.f;
    }
    for (int k0 = 0; k0 < ci; k0 += 32) {
      if (t < 256) {  // W stage: 32 rows x 32 k
        const int row = t >> 3;
        const int kk = (t & 7) * 4;
        const float* srcp = A + (size_t)(c0 + row) * lda + k0 + kk;
        float4 w4;
        if (k0 + kk + 4 <= ci) {
          w4 = *(const float4*)srcp;
        } else {
          w4.x = (k0 + kk + 0 < ci) ? srcp[0] : 0.f;
          w4.y = (k0 + kk + 1 < ci) ? srcp[1] : 0.f;
          w4.z = (k0 + kk + 2 < ci) ? srcp[2] : 0.f;
          w4.w = (k0 + kk + 3 < ci) ? srcp[3] : 0.f;
        }
        Wt[kk + 0][row] = w4.x; Wt[kk + 1][row] = w4.y;
        Wt[kk + 2][row] = w4.z; Wt[kk + 3][row] = w4.w;
      }
      {  // X stage
        const int kk = t >> 4, nl = (t & 15) * 4;
        float4 x4 = make_float4(0.f, 0.f, 0.f, 0.f);
        if (k0 + kk < ci) x4 = *(const float4*)(X + (size_t)(k0 + kk) * 1024 + n0 + nl);
        *(float4*)&Xs[kk][nl] = x4;
      }
      __syncthreads();
      #pragma unroll
      for (int kk = 0; kk < 32; ++kk) {
        const float w0 = Wt[kk][ty];
        const float4 x4 = *(const float4*)&Xs[kk][tx * 4];
        acc[0] = fmaf(w0, x4.x, acc[0]);
        acc[1] = fmaf(w0, x4.y, acc[1]);
        acc[2] = fmaf(w0, x4.z, acc[2]);
        acc[3] = fmaf(w0, x4.w, acc[3]);
      }
      __syncthreads();
    }
    if (split) {
      #pragma unroll
      for (int jj = 0; jj < 4; ++jj)
        accT[jj] = __fadd_rn(accT[jj], acc[jj]);
    }
  }
  {
    const int row = c0 + ty;
    const float b = jb.bias ? jb.bias[row] : 0.f;
    const float* src = split ? accT : acc;
    float4 o;
    o.x = __fadd_rn(src[0], b); o.y = __fadd_rn(src[1], b);
    o.z = __fadd_rn(src[2], b); o.w = __fadd_rn(src[3], b);
    if (jb.resid) {
      const float4 r4 = *(const float4*)(jb.resid + (size_t)row * 1024 + n0 + tx * 4);
      o.x = __fadd_rn(r4.x, o.x); o.y = __fadd_rn(r4.y, o.y);
      o.z = __fadd_rn(r4.z, o.z); o.w = __fadd_rn(r4.w, o.w);
    }
    *(float4*)(jb.C + (size_t)row * 1024 + n0 + tx * 4) = o;
  }
}

// ========== C[n][m] = scale * sum_k A[(cb+k*cs)*1024+n]*B[(cb+k*cs)*1024+m] ==
__global__ __launch_bounds__(256) void gemm_tn(TArgs args, int K, int cs,
                                               float scale, int ldc) {
  __shared__ float As[64][68];
  __shared__ float Bs[64][68];
  TJob jb = args.j[blockIdx.z];
  const int m0 = blockIdx.x * 64;
  const int n0 = blockIdx.y * 64;
  const int t = threadIdx.x, tx = t & 15, ty = t >> 4;
  float acc[4][4] = {};
  for (int k0 = 0; k0 < K; k0 += 64) {
    #pragma unroll
    for (int q = 0; q < 4; ++q) {
      const int kk = (t >> 4) + q * 16;
      const int col = (t & 15) * 4;
      const size_t rb = (size_t)(jb.cb + (k0 + kk) * cs) * 1024;
      *(float4*)&As[kk][col] = *(const float4*)(jb.A + rb + n0 + col);
      *(float4*)&Bs[kk][col] = *(const float4*)(jb.B + rb + m0 + col);
    }
    __syncthreads();
    #pragma unroll 16
    for (int kk = 0; kk < 64; ++kk) {
      const float4 w4 = *(const float4*)&As[kk][ty * 4];
      const float4 x4 = *(const float4*)&Bs[kk][tx * 4];
      MICRO_FMA(w4, x4)
    }
    __syncthreads();
  }
  #pragma unroll
  for (int i = 0; i < 4; ++i) {
    float4 o;
    o.x = __fmul_rn(acc[i][0], scale); o.y = __fmul_rn(acc[i][1], scale);
    o.z = __fmul_rn(acc[i][2], scale); o.w = __fmul_rn(acc[i][3], scale);
    *(float4*)(jb.C + (size_t)(n0 + ty * 4 + i) * ldc + m0 + tx * 4) = o;
  }
}

// == msg: C[d][n] = sum_m V[d*4096+m] P[n*1024+m]; 512 thr, 32x64, 1x4 micro ==
// Vs pad 33 (write banks spread); Ps pad 68 keeps float4-aligned reads.
__global__ __launch_bounds__(512) void gemm_vp(VArgs args) {
  __shared__ float Vs[64][33];
  __shared__ float Ps[64][68];
  VJob jb = args.j[blockIdx.z];
  const int n0 = blockIdx.x * 64;
  const int d0 = blockIdx.y * 32;
  const int t = threadIdx.x, tx = t & 15, ty = t >> 4;   // ty 0..31
  float acc[4] = {};
  for (int m0 = 0; m0 < 1024; m0 += 64) {
    {  // V stage: one float4 per thread
      const int d = t >> 4, m4 = (t & 15) * 4;
      float4 v4 = *(const float4*)(jb.V + (size_t)(d0 + d) * 4096 + m0 + m4);
      Vs[m4 + 0][d] = v4.x; Vs[m4 + 1][d] = v4.y;
      Vs[m4 + 2][d] = v4.z; Vs[m4 + 3][d] = v4.w;
    }
    #pragma unroll
    for (int q = 0; q < 2; ++q) {  // P stage: two float4 per thread
      const int idx = t + q * 512;
      const int n = idx >> 4, m4 = (idx & 15) * 4;
      float4 p4 = *(const float4*)(jb.P + (size_t)(n0 + n) * 1024 + m0 + m4);
      Ps[m4 + 0][n] = p4.x; Ps[m4 + 1][n] = p4.y;
      Ps[m4 + 2][n] = p4.z; Ps[m4 + 3][n] = p4.w;
    }
    __syncthreads();
    #pragma unroll
    for (int mm = 0; mm < 64; ++mm) {
      const float v = Vs[mm][ty];
      const float4 p4 = *(const float4*)&Ps[mm][tx * 4];
      acc[0] = fmaf(v, p4.x, acc[0]);
      acc[1] = fmaf(v, p4.y, acc[1]);
      acc[2] = fmaf(v, p4.z, acc[2]);
      acc[3] = fmaf(v, p4.w, acc[3]);
    }
    __syncthreads();
  }
  {
    float4 o;
    o.x = acc[0]; o.y = acc[1]; o.z = acc[2]; o.w = acc[3];
    *(float4*)(jb.C + (size_t)(d0 + ty) * 4096 + n0 + tx * 4) = o;
  }
}

// == prop: C[c][d] = scale * sum_s A[c][s]B[d][s]; 128 thr, 32x64 tile ========
__global__ __launch_bounds__(128) void gemm_nt(NArgs args, float scale) {
  __shared__ float Cs[64][36];
  __shared__ float Ds[64][68];
  NJob jb = args.j[blockIdx.z];
  const int d0 = blockIdx.x * 64;
  const int c0 = blockIdx.y * 32;
  const int t = threadIdx.x, tx = t & 15, ty = t >> 4;
  float acc[4][4] = {};
  for (int s0 = 0; s0 < 1024; s0 += 64) {
    #pragma unroll
    for (int q = 0; q < 4; ++q) {
      const int idx = t + q * 128;
      const int c = idx >> 4, s4 = (idx & 15) * 4;
      float4 a4 = *(const float4*)(jb.A + (size_t)(c0 + c) * 1024 + s0 + s4);
      Cs[s4 + 0][c] = a4.x; Cs[s4 + 1][c] = a4.y;
      Cs[s4 + 2][c] = a4.z; Cs[s4 + 3][c] = a4.w;
    }
    #pragma unroll
    for (int q = 0; q < 8; ++q) {
      const int idx = t + q * 128;
      const int d = idx >> 4, s4 = (idx & 15) * 4;
      float4 b4 = *(const float4*)(jb.B + (size_t)(d0 + d) * 1024 + s0 + s4);
      Ds[s4 + 0][d] = b4.x; Ds[s4 + 1][d] = b4.y;
      Ds[s4 + 2][d] = b4.z; Ds[s4 + 3][d] = b4.w;
    }
    __syncthreads();
    #pragma unroll
    for (int ss = 0; ss < 64; ++ss) {
      const float4 w4 = *(const float4*)&Cs[ss][ty * 4];
      const float4 x4 = *(const float4*)&Ds[ss][tx * 4];
      MICRO_FMA(w4, x4)
    }
    __syncthreads();
  }
  #pragma unroll
  for (int i = 0; i < 4; ++i) {
    float4 o;
    o.x = __fmul_rn(acc[i][0], scale); o.y = __fmul_rn(acc[i][1], scale);
    o.z = __fmul_rn(acc[i][2], scale); o.w = __fmul_rn(acc[i][3], scale);
    *(float4*)(jb.C + (size_t)(c0 + ty * 4 + i) * 1024 + d0 + tx * 4) = o;
  }
}

// ===== build adjacency ones ==================================================
__global__ __launch_bounds__(64) void scatter_adj(const int* __restrict__ nbr,
                                                  float* __restrict__ adj) {
  const int i = blockIdx.x, img = blockIdx.y;
  const int t = threadIdx.x;
  if (t >= 20) return;
  const int dst = nbr[((size_t)img * 1024 + i) * 20 + t];
  adj[(size_t)img * 1048576 + (size_t)dst * 1024 + i] = 1.0f;
}

// == bn+relu: stage to LDS; ONE wave runs the exact sequential chains =========
__global__ __launch_bounds__(256) void bn_relu_par(float* __restrict__ x,
                                                   const float* __restrict__ g,
                                                   const float* __restrict__ be,
                                                   int co) {
  const int ch = blockIdx.x, img = blockIdx.y;
  float* p = x + ((size_t)img * co + ch) * 1024;
  __shared__ float ls[1024];
  __shared__ float sh[2];
  const int t = threadIdx.x;
  #pragma unroll
  for (int q = 0; q < 4; ++q) ls[t + q * 256] = p[t + q * 256];
  __syncthreads();
  if (t < 64) {
    float s = 0.f;
    for (int n = 0; n < 1024; ++n) s = __fadd_rn(s, ls[n]);
    const float mean = __fdiv_rn(s, 1024.f);
    float vs = 0.f;
    for (int n = 0; n < 1024; ++n) {
      const float d = __fsub_rn(ls[n], mean);
      vs = __fadd_rn(vs, __fmul_rn(d, d));
    }
    const float var = __fdiv_rn(vs, 1024.f);
    if (t == 0) {
      sh[0] = mean;
      sh[1] = __fdiv_rn(1.f, sqrtf(__fadd_rn(var, 1e-5f)));
    }
  }
  __syncthreads();
  const float mean = sh[0], rs = sh[1];
  const float gc = g[ch], bc = be[ch];
  #pragma unroll
  for (int q = 0; q < 4; ++q) {
    const int n = t + q * 256;
    float v = __fmul_rn(gc, __fsub_rn(ls[n], mean));
    v = __fmul_rn(v, rs);
    v = __fadd_rn(v, bc);
    p[n] = fmaxf(v, 0.f);
  }
}

// == KNN top-20 (unchanged) ===================================================
__global__ __launch_bounds__(256) void knn_kernel(const float* __restrict__ uc1,
                                                  const float* __restrict__ uc2,
                                                  int* __restrict__ nbr) {
  const int i = blockIdx.x, img = blockIdx.y;
  const float* uc = img ? uc2 : uc1;
  __shared__ float dist[1024];
  __shared__ float rv[256];
  __shared__ int   ri[256];
  const int t = threadIdx.x;
  const float pix = uc[i * 3], piy = uc[i * 3 + 1], piz = uc[i * 3 + 2];
  const float sqi = fmaf(piz, piz, fmaf(piy, piy, __fmul_rn(pix, pix)));
  for (int j = t; j < 1024; j += 256) {
    const float x = uc[j * 3], y = uc[j * 3 + 1], z = uc[j * 3 + 2];
    const float gg  = fmaf(piz, z, fmaf(piy, y, __fmul_rn(pix, x)));
    const float sqj = fmaf(z, z, fmaf(y, y, __fmul_rn(x, x)));
    const float d = __fsub_rn(__fadd_rn(sqi, sqj), __fmul_rn(2.f, gg));
    dist[j] = (j == i) ? INFINITY : d;
  }
  __syncthreads();
  int* out = nbr + ((size_t)img * 1024 + i) * 20;
  for (int k = 0; k < 20; ++k) {
    float bv = INFINITY; int bi = 0x7fffffff;
    for (int j = t; j < 1024; j += 256) {
      const float d = dist[j];
      if (d < bv) { bv = d; bi = j; }
    }
    rv[t] = bv; ri[t] = bi;
    __syncthreads();
    for (int st = 128; st > 0; st >>= 1) {
      if (t < st) {
        const float v2 = rv[t + st]; const int i2 = ri[t + st];
        if (v2 < rv[t] || (v2 == rv[t] && i2 < ri[t])) { rv[t] = v2; ri[t] = i2; }
      }
      __syncthreads();
    }
    if (t == 0) { out[k] = ri[0]; dist[ri[0]] = INFINITY; }
    __syncthreads();
  }
}

// ======================= o = a*x + b*y, no-FMA per-op rounding ===============
__global__ __launch_bounds__(256) void axpby(const float* __restrict__ x,
                                             const float* __restrict__ y,
                                             float* __restrict__ o,
                                             float a, float b, int n) {
  const int i = blockIdx.x * 256 + threadIdx.x;
  if (i < n) o[i] = __fadd_rn(__fmul_rn(a, x[i]), __fmul_rn(b, y[i]));
}

// == softmax row: tree-max + parallel exp; ONE wave runs the exact sum chain ==
__global__ __launch_bounds__(256) void softmax_par(float* __restrict__ P) {
  float* p = P + (size_t)blockIdx.x * 1024;
  __shared__ float ls[1024];
  __shared__ float red[256];
  const int t = threadIdx.x;
  float mx = -INFINITY;
  #pragma unroll
  for (int q = 0; q < 4; ++q) {
    const float v = p[t + q * 256];
    ls[t + q * 256] = v;
    mx = fmaxf(mx, v);
  }
  red[t] = mx;
  __syncthreads();
  for (int st = 128; st > 0; st >>= 1) { if (t < st) red[t] = fmaxf(red[t], red[t + st]); __syncthreads(); }
  mx = red[0];
  __syncthreads();
  #pragma unroll
  for (int q = 0; q < 4; ++q) {
    const int n = t + q * 256;
    ls[n] = exp_cr(__fsub_rn(ls[n], mx));
  }
  __syncthreads();
  if (t < 64) {
    float s = 0.f;
    for (int n = 0; n < 1024; ++n) s = __fadd_rn(s, ls[n]);  // exact serial chain
    if (t == 0) red[0] = s;
  }
  __syncthreads();
  const float s = red[0];
  #pragma unroll
  for (int q = 0; q < 4; ++q) {
    const int n = t + q * 256;
    p[n] = __fdiv_rn(ls[n], s);
  }
}

// ======================= build Z and Z^T (f32 copies) ========================
__global__ __launch_bounds__(256) void build_Z(const float* __restrict__ sc,
                                               const float* __restrict__ alpha,
                                               float* __restrict__ Z,
                                               float* __restrict__ ZT) {
  const int idx = blockIdx.x * 256 + threadIdx.x;
  if (idx >= 1025 * 1025) return;
  const int i = idx / 1025, j = idx - i * 1025;
  const float v = (i < 1024 && j < 1024) ? sc[(size_t)i * 1024 + j] : alpha[0];
  Z[idx] = v;
  ZT[(size_t)j * 1025 + i] = v;
}

// == lse row: stage + tree-max + parallel exp; ONE wave runs exact sum chain ==
__global__ __launch_bounds__(256) void lse_par(const float* __restrict__ M,
                                               const float* __restrict__ add,
                                               float* __restrict__ out) {
  const int r = blockIdx.x;
  const float* p = M + (size_t)r * 1025;
  __shared__ float ls[1025];
  __shared__ float red[256];
  const int t = threadIdx.x;
  float mx = -INFINITY;
  for (int j = t; j < 1025; j += 256) {
    const float v = __fadd_rn(p[j], add[j]);
    ls[j] = v;
    mx = fmaxf(mx, v);
  }
  red[t] = mx;
  __syncthreads();
  for (int st = 128; st > 0; st >>= 1) { if (t < st) red[t] = fmaxf(red[t], red[t + st]); __syncthreads(); }
  mx = red[0];
  __syncthreads();
  for (int j = t; j < 1025; j += 256) ls[j] = exp_cr(__fsub_rn(ls[j], mx));
  __syncthreads();
  if (t < 64) {
    float s = 0.f;
    for (int j = 0; j < 1025; ++j) s = __fadd_rn(s, ls[j]);  // exact serial chain
    if (t == 0) {
      const float logw = (r < 1024) ? NORM_F : BIN_F;
      out[r] = __fsub_rn(logw, __fadd_rn(log_cr(s), mx));
    }
  }
}

// == final Z = ((Z + u) + v) - norm_f32; outZ + col-major copy ================
__global__ __launch_bounds__(256) void write_final(const float* __restrict__ Z,
                                                   const float* __restrict__ u,
                                                   const float* __restrict__ v,
                                                   float* __restrict__ outZ,
                                                   float* __restrict__ FZc) {
  const int idx = blockIdx.x * 256 + threadIdx.x;
  if (idx >= 1025 * 1025) return;
  const int i = idx / 1025, j = idx - i * 1025;
  float t = __fadd_rn(Z[idx], u[i]);
  t = __fadd_rn(t, v[j]);
  t = __fsub_rn(t, NORM_F);
  outZ[idx] = t;
  FZc[(size_t)j * 1025 + i] = t;
}

// == argmax row: tie-aware tree (== first-index sequential) ===================
__global__ __launch_bounds__(256) void argmax_par(const float* __restrict__ M,
                                                  float* __restrict__ maxout,
                                                  int* __restrict__ idxout) {
  const int r = blockIdx.x;
  const float* p = M + (size_t)r * 1025;
  __shared__ float rv[256];
  __shared__ int   ri[256];
  const int t = threadIdx.x;
  float bv = -INFINITY; int bi = 0x7fffffff;
  for (int j = t; j < 1024; j += 256) {
    const float v = p[j];
    if (v > bv) { bv = v; bi = j; }
  }
  rv[t] = bv; ri[t] = bi;
  __syncthreads();
  for (int st = 128; st > 0; st >>= 1) {
    if (t < st) {
      const float v2 = rv[t + st]; const int i2 = ri[t + st];
      if (v2 > rv[t] || (v2 == rv[t] && i2 < ri[t])) { rv[t] = v2; ri[t] = i2; }
    }
    __syncthreads();
  }
  if (t == 0) {
    idxout[r] = ri[0];
    if (maxout) maxout[r] = rv[0];
  }
}

// ======================= mutual matching =====================================
__global__ __launch_bounds__(256) void matches_kernel(const int* __restrict__ idx1,
                                                      const int* __restrict__ idx2,
                                                      const float* __restrict__ rowmax,
                                                      float* __restrict__ m_out,
                                                      float* __restrict__ s_out) {
  const int i = blockIdx.x * 256 + threadIdx.x;
  if (i >= 1024) return;
  const int j = idx1[i];
  const bool mutual = (idx2[j] == i);
  const float msc = mutual ? exp_cr(rowmax[i]) : 0.f;
  s_out[i] = msc;
  m_out[i] = (mutual && msc > 0.2f) ? (float)j : -1.f;
}

// ============================================================================
extern "C" void kernel_launch(void* const* d_in, const int* in_sizes, int n_in,
                              void* d_out, int out_size, void* d_ws, size_t ws_size,
                              hipStream_t stream) {
  const float* h1  = (const float*)d_in[0];
  const float* h2  = (const float*)d_in[1];
  const float* uc1 = (const float*)d_in[2];
  const float* uc2 = (const float*)d_in[3];
  const float* s1  = (const float*)d_in[4];
  const float* s2  = (const float*)d_in[5];
  const float* kw[5]  = { (const float*)d_in[6],  (const float*)d_in[8],
                          (const float*)d_in[10], (const float*)d_in[12],
                          (const float*)d_in[14] };
  const float* kb[5]  = { (const float*)d_in[7],  (const float*)d_in[9],
                          (const float*)d_in[11], (const float*)d_in[13],
                          (const float*)d_in[15] };
  const float* kg[4]  = { (const float*)d_in[16], (const float*)d_in[18],
                          (const float*)d_in[20], (const float*)d_in[22] };
  const float* kbe[4] = { (const float*)d_in[17], (const float*)d_in[19],
                          (const float*)d_in[21], (const float*)d_in[23] };
  const float* cheb_w = (const float*)d_in[24];
  const float* cheb_b = (const float*)d_in[25];
  const float* pw = (const float*)d_in[26];
  const float* pb = (const float*)d_in[27];
  const float* mw = (const float*)d_in[28];
  const float* mb = (const float*)d_in[29];
  const float* m1w = (const float*)d_in[30];
  const float* m1b = (const float*)d_in[31];
  const float* gg  = (const float*)d_in[32];
  const float* gbe = (const float*)d_in[33];
  const float* m2w = (const float*)d_in[34];
  const float* m2b = (const float*)d_in[35];
  const float* fpw = (const float*)d_in[36];
  const float* fpb = (const float*)d_in[37];
  const float* bin = (const float*)d_in[38];

  float* ws = (float*)d_ws;
  float* A0   = ws;                 // 1048576
  float* A1   = ws + 1048576;       // 1048576
  float* Dm   = ws + 2097152;       // 524288
  float* DT   = ws + 2621440;       // 524288
  float* TX1  = ws + 3145728;       // 524288
  float* TX2  = ws + 3670016;       // 524288
  float* QKV  = ws + 4194304;       // 1572864
  float* PROB = ws + 5767168;       // 8388608 (adjacency early; probs; SC late)
  float* ADJ = PROB;
  float* SCp = PROB;
  float* Zb  = ws;                  // 1050625
  float* ZTb = ws + 1050628;        // 1050625
  float* FZc = ws + 3151884;        // 1050625
  float* Ub  = ws + 4202512;        // 1025
  float* Vb  = ws + 4203540;        // 1025
  float* RM  = ws + 4204568;        // 1024
  int*   I1  = (int*)(ws + 4205592);
  int*   I2  = (int*)(ws + 4206616);
  int*   KNNI = (int*)QKV;
  float* MSG   = A1;
  float* T1    = A0;
  float* outF  = (float*)d_out;
  float* outZ  = outF;
  float* outM  = outF + 1050625;
  float* outS  = outF + 1051649;
  float* outMD1 = outF + 1052673;
  float* outMD2 = outF + 1314817;
  (void)ws_size; (void)in_sizes; (void)n_in; (void)out_size;

  // ---------------- 1. kenc ----------------
  concat_kenc<<<dim3(1040, 2), 256, 0, stream>>>(h1, h2, uc1, uc2, s1, s2, A0);

  const int kci[5] = { 260, 64, 128, 256, 512 };
  const int kco[5] = { 64, 128, 256, 512, 256 };
  float* ping = A0; float* pong = A1;
  for (int L = 0; L < 5; ++L) {
    const int ci = kci[L], co = kco[L];
    float* dst = (L == 4) ? DT : pong;
    GArgs ga = {};
    for (int img = 0; img < 2; ++img) {
      ga.j[img].A0 = kw[L];
      ga.j[img].X0 = ping + (size_t)img * ci * 1024;
      ga.j[img].bias = kb[L];
      ga.j[img].C = dst + (size_t)img * co * 1024;
    }
    gemm_std<<<dim3(16, co / 32, 2), 512, 0, stream>>>(ga, 1, 0, ci, 0, 0, ci, co);
    if (L < 4)
      bn_relu_par<<<dim3(co, 2), 256, 0, stream>>>(dst, kg[L], kbe[L], co);
    float* tmp = ping; ping = pong; pong = tmp;
  }

  // ---------------- 2. knn + chebconv ----------------
  knn_kernel<<<dim3(1024, 2), 256, 0, stream>>>(uc1, uc2, KNNI);
  hipMemsetAsync(ADJ, 0, 2u * 1048576u * sizeof(float), stream);
  scatter_adj<<<dim3(1024, 2), 64, 0, stream>>>(KNNI, ADJ);

  {
    NArgs na = {};
    for (int img = 0; img < 2; ++img) {
      na.j[img].A = DT + (size_t)img * 262144;
      na.j[img].B = ADJ + (size_t)img * 1048576;
      na.j[img].C = TX1 + (size_t)img * 262144;
    }
    gemm_nt<<<dim3(16, 8, 2), 128, 0, stream>>>(na, -0.05f);
  }
  {
    NArgs na = {};
    for (int img = 0; img < 2; ++img) {
      na.j[img].A = TX1 + (size_t)img * 262144;
      na.j[img].B = ADJ + (size_t)img * 1048576;
      na.j[img].C = A0 + (size_t)img * 262144;
    }
    gemm_nt<<<dim3(16, 8, 2), 128, 0, stream>>>(na, -0.05f);
  }
  axpby<<<2048, 256, 0, stream>>>(A0, DT, TX2, 2.f, -1.f, 524288);

  {
    GArgs ga = {};
    for (int img = 0; img < 2; ++img) {
      ga.j[img].A0 = cheb_w;           ga.j[img].X0 = DT  + (size_t)img * 262144;
      ga.j[img].A1 = cheb_w + 65536;   ga.j[img].X1 = TX1 + (size_t)img * 262144;
      ga.j[img].A2 = cheb_w + 131072;  ga.j[img].X2 = TX2 + (size_t)img * 262144;
      ga.j[img].bias = cheb_b;
      ga.j[img].C = Dm + (size_t)img * 262144;
    }
    gemm_std<<<dim3(16, 8, 2), 512, 0, stream>>>(ga, 3, 1, 256, 256, 256, 256, 256);
  }

  // ---------------- 3. GNN layers ----------------
  float* qb = QKV;
  float* kb_ = QKV + 524288;
  float* vb = QKV + 1048576;
  float* MSG2 = QKV;
  for (int l = 0; l < 18; ++l) {
    const int cross = l & 1;
    const float* x[2]   = { Dm, Dm + 262144 };
    const float* src[2] = { cross ? x[1] : x[0], cross ? x[0] : x[1] };

    {
      GArgs ga = {};
      for (int p = 0; p < 3; ++p)
        for (int img = 0; img < 2; ++img) {
          GJob& j = ga.j[p * 2 + img];
          j.A0 = pw + ((size_t)(l * 3 + p)) * 65536;
          j.X0 = (p == 0) ? x[img] : src[img];
          j.bias = pb + ((size_t)(l * 3 + p)) * 256;
          j.C = QKV + ((size_t)(p * 2 + img)) * 262144;
        }
      gemm_std<<<dim3(16, 8, 6), 512, 0, stream>>>(ga, 1, 0, 256, 0, 0, 256, 256);
    }
    {
      TArgs ta = {};
      for (int img = 0; img < 2; ++img)
        for (int h = 0; h < 4; ++h) {
          TJob& j = ta.j[img * 4 + h];
          j.A = qb + (size_t)img * 262144;
          j.B = kb_ + (size_t)img * 262144;
          j.C = PROB + ((size_t)(img * 4 + h)) * 1048576;
          j.cb = h;
        }
      gemm_tn<<<dim3(16, 16, 8), 256, 0, stream>>>(ta, 64, 4, 0.125f, 1024);
    }
    softmax_par<<<8192, 256, 0, stream>>>(PROB);
    {
      VArgs va = {};
      for (int img = 0; img < 2; ++img)
        for (int h = 0; h < 4; ++h) {
          VJob& j = va.j[img * 4 + h];
          j.V = vb + (size_t)img * 262144 + h * 1024;
          j.P = PROB + ((size_t)(img * 4 + h)) * 1048576;
          j.C = MSG + (size_t)img * 262144 + h * 1024;
        }
      gemm_vp<<<dim3(16, 2, 8), 512, 0, stream>>>(va);
    }
    {
      GArgs ga = {};
      for (int img = 0; img < 2; ++img) {
        ga.j[img].A0 = mw + (size_t)l * 65536;
        ga.j[img].X0 = MSG + (size_t)img * 262144;
        ga.j[img].bias = mb + (size_t)l * 256;
        ga.j[img].C = MSG2 + (size_t)img * 262144;
      }
      gemm_std<<<dim3(16, 8, 2), 512, 0, stream>>>(ga, 1, 0, 256, 0, 0, 256, 256);
    }
    {
      GArgs ga = {};
      for (int img = 0; img < 2; ++img) {
        ga.j[img].A0 = m1w + (size_t)l * 262144;        ga.j[img].X0 = x[img];
        ga.j[img].A1 = m1w + (size_t)l * 262144 + 256;  ga.j[img].X1 = MSG2 + (size_t)img * 262144;
        ga.j[img].bias = m1b + (size_t)l * 512;
        ga.j[img].C = T1 + (size_t)img * 524288;
      }
      gemm_std<<<dim3(16, 16, 2), 512, 0, stream>>>(ga, 2, 0, 256, 256, 0, 512, 512);
    }
    bn_relu_par<<<dim3(512, 2), 256, 0, stream>>>(T1, gg + (size_t)l * 512, gbe + (size_t)l * 512, 512);
    {
      // m2 with fused residual: Dm = Dm + (acc + bias)
      GArgs ga = {};
      for (int img = 0; img < 2; ++img) {
        ga.j[img].A0 = m2w + (size_t)l * 131072;
        ga.j[img].X0 = T1 + (size_t)img * 524288;
        ga.j[img].bias = m2b + (size_t)l * 256;
        ga.j[img].C = Dm + (size_t)img * 262144;
        ga.j[img].resid = Dm + (size_t)img * 262144;
      }
      gemm_std<<<dim3(16, 8, 2), 512, 0, stream>>>(ga, 1, 0, 512, 0, 0, 512, 256);
    }
  }

  // ---------------- 4. final projections + score matrix ----------------
  {
    GArgs ga = {};
    for (int img = 0; img < 2; ++img) {
      ga.j[img].A0 = fpw;
      ga.j[img].X0 = Dm + (size_t)img * 262144;
      ga.j[img].bias = fpb;
      ga.j[img].C = (img ? outMD2 : outMD1);
    }
    gemm_std<<<dim3(16, 8, 2), 512, 0, stream>>>(ga, 1, 0, 256, 0, 0, 256, 256);
  }
  {
    TArgs ta = {};
    ta.j[0].A = outMD1; ta.j[0].B = outMD2; ta.j[0].C = SCp; ta.j[0].cb = 0;
    gemm_tn<<<dim3(16, 16, 1), 256, 0, stream>>>(ta, 256, 1, 0.0625f, 1024);
  }

  // ---------------- 5. Sinkhorn ----------------
  build_Z<<<4105, 256, 0, stream>>>(SCp, bin, Zb, ZTb);
  hipMemsetAsync(Ub, 0, 1025 * sizeof(float), stream);
  hipMemsetAsync(Vb, 0, 1025 * sizeof(float), stream);
  for (int it = 0; it < 20; ++it) {
    lse_par<<<1025, 256, 0, stream>>>(Zb, Vb, Ub);
    lse_par<<<1025, 256, 0, stream>>>(ZTb, Ub, Vb);
  }
  write_final<<<4105, 256, 0, stream>>>(Zb, Ub, Vb, outZ, FZc);

  // ---------------- 6. matching ----------------
  argmax_par<<<1024, 256, 0, stream>>>(outZ, RM, I1);
  argmax_par<<<1024, 256, 0, stream>>>(FZc, (float*)nullptr, I2);
  matches_kernel<<<4, 256, 0, stream>>>(I1, I2, RM, outM, outS);
}